// Round 7
// baseline (437.454 us; speedup 1.0000x reference)
//
#include <hip/hip_runtime.h>
#include <hip/hip_bf16.h>

// Performer causal attention, chunked scan, MFMA bf16 everywhere.
// B=4 T=4096 H=12 E=64 M=266 (padded 288). mfma_f32_16x16x32_bf16.
// R6: phi_k materialized by dedicated phik_fill kernel; stage_c4 (barrier-light,
//     global-fed) runs over bh-slices sized at runtime from ws_size.
//     kn/diagk buffers removed (raw-k staging inline). R4 fallback deleted.

typedef unsigned short u16;
typedef __attribute__((ext_vector_type(8))) short bf16x8;   // 8 bf16 = 4 VGPR
typedef __attribute__((ext_vector_type(4))) float f32x4;

constexpr int Tn = 4096, Hn = 12;
constexpr int MP = 288;       // padded feature dim
constexpr int Mn = 266;
constexpr int CH = 128;       // chunk length
constexpr int NC = 32;        // chunks
constexpr int BH = 48;

constexpr float DATA_NORM = 0.35355339059327379f;  // 64^-0.25
constexpr float SM_EPS = 1e-4f;
constexpr float N_EPS  = 1e-6f;
constexpr float RATIO  = 0.06131393152401153f;     // 266^-0.5

// flat causal tile list (tt, tp) tp<=tt (validated in R2)
__constant__ signed char cTT[36] = {0,1,1,2,2,2,3,3,3,3,4,4,4,4,4,5,5,5,5,5,5,6,6,6,6,6,6,6,7,7,7,7,7,7,7,7};
__constant__ signed char cTP[36] = {0,0,1,0,1,2,0,1,2,3,0,1,2,3,4,0,1,2,3,4,5,0,1,2,3,4,5,6,0,1,2,3,4,5,6,7};

__device__ __forceinline__ u16 f2bf(float f) {
  __hip_bfloat16 h = __float2bfloat16(f);
  return __builtin_bit_cast(u16, h);
}
__device__ __forceinline__ float bf2f(u16 u) {
  return __uint_as_float(((unsigned)u) << 16);
}
__device__ __forceinline__ bf16x8 ldb(const u16* p) {
  return *reinterpret_cast<const bf16x8*>(p);
}
__device__ __forceinline__ f32x4 mfma16(bf16x8 a, bf16x8 b, f32x4 c) {
  return __builtin_amdgcn_mfma_f32_16x16x32_bf16(a, b, c, 0, 0, 0);
}
__device__ __forceinline__ void atomicMaxF(float* addr, float val) {
  if (val >= 0.f) atomicMax(reinterpret_cast<int*>(addr), __float_as_int(val));
  else atomicMin(reinterpret_cast<unsigned int*>(addr), __float_as_uint(val));
}

// ---------------- prep: projbf [288][64] bf16 zero-padded; kmax init ----------------
__global__ void prep(const float* __restrict__ proj, u16* __restrict__ projbf,
                     float* __restrict__ kmax) {
  int idx = blockIdx.x * 256 + threadIdx.x;
  if (idx < MP * 64) {
    int m = idx >> 6, e = idx & 63;
    float v = (m < Mn) ? proj[m * 64 + e] : 0.f;
    projbf[idx] = f2bf(v);
  }
  if (blockIdx.x == 0 && threadIdx.x < BH) kmax[threadIdx.x] = -3.0e38f;
}

// ---------------- feat_q: phi_q = ratio*(exp(dd - diag - rowmax) + eps) ----------------
__global__ __launch_bounds__(256) void feat_q(
    const float* __restrict__ q, const u16* __restrict__ projbf,
    u16* __restrict__ phiq) {
  __shared__ __align__(16) u16 xt[64 * 72];
  __shared__ float diag[64];
  const int tid = threadIdx.x;
  const int bh = blockIdx.x >> 6, tb = blockIdx.x & 63;
  const int b = bh / Hn, h = bh % Hn;
  const int t0 = tb * 64;
  {
    const int t = tid >> 2, e0 = (tid & 3) * 16;
    const float* row = q + (((size_t)b * Tn + t0 + t) * Hn + h) * 64 + e0;
    float ss = 0.f;
#pragma unroll
    for (int q4 = 0; q4 < 4; ++q4) {
      float4 vv = *reinterpret_cast<const float4*>(row + q4 * 4);
      float x0 = vv.x * DATA_NORM, x1 = vv.y * DATA_NORM;
      float x2 = vv.z * DATA_NORM, x3 = vv.w * DATA_NORM;
      ss += x0 * x0 + x1 * x1 + x2 * x2 + x3 * x3;
      ushort4 uu = make_ushort4(f2bf(x0), f2bf(x1), f2bf(x2), f2bf(x3));
      *reinterpret_cast<ushort4*>(&xt[t * 72 + e0 + q4 * 4]) = uu;
    }
    ss += __shfl_xor(ss, 1);
    ss += __shfl_xor(ss, 2);
    if ((tid & 3) == 0) diag[t] = 0.5f * ss;
  }
  __syncthreads();
  const int lane = tid & 63, wv = tid >> 6;
  const int lj = lane & 15, lg = lane >> 4;
  bf16x8 a0 = ldb(&xt[(wv * 16 + lj) * 72 + lg * 8]);
  bf16x8 a1 = ldb(&xt[(wv * 16 + lj) * 72 + 32 + lg * 8]);
  f32x4 acc[17];
#pragma unroll
  for (int mt = 0; mt < 17; ++mt) {
    const u16* br = &projbf[(mt * 16 + lj) * 64 + lg * 8];
    f32x4 z = {0.f, 0.f, 0.f, 0.f};
    z = mfma16(a0, ldb(br), z);
    z = mfma16(a1, ldb(br + 32), z);
    acc[mt] = z;
  }
  float rmax[4] = {-3e38f, -3e38f, -3e38f, -3e38f};
#pragma unroll
  for (int mt = 0; mt < 17; ++mt) {
    int m = mt * 16 + lj;
    if (m < Mn) {
#pragma unroll
      for (int r = 0; r < 4; ++r) rmax[r] = fmaxf(rmax[r], acc[mt][r]);
    }
  }
#pragma unroll
  for (int r = 0; r < 4; ++r) {
    rmax[r] = fmaxf(rmax[r], __shfl_xor(rmax[r], 1));
    rmax[r] = fmaxf(rmax[r], __shfl_xor(rmax[r], 2));
    rmax[r] = fmaxf(rmax[r], __shfl_xor(rmax[r], 4));
    rmax[r] = fmaxf(rmax[r], __shfl_xor(rmax[r], 8));
  }
  float dg[4];
#pragma unroll
  for (int r = 0; r < 4; ++r) dg[r] = diag[wv * 16 + lg * 4 + r];
  u16* ob = phiq + ((size_t)bh * Tn + t0 + wv * 16) * MP;
#pragma unroll
  for (int mt = 0; mt < 17; ++mt) {
    int m = mt * 16 + lj;
#pragma unroll
    for (int r = 0; r < 4; ++r) {
      float val = 0.f;
      if (m < Mn)
        val = RATIO * (__expf(acc[mt][r] - dg[r] - rmax[r]) + SM_EPS);
      ob[(size_t)(lg * 4 + r) * MP + m] = f2bf(val);
    }
  }
#pragma unroll
  for (int r = 0; r < 4; ++r)   // m-tile 17 = all pad -> zeros
    ob[(size_t)(lg * 4 + r) * MP + 272 + lj] = 0;
}

// ---------------- feat_k: pure global max of dd ----------------
__global__ __launch_bounds__(256) void feat_k(
    const float* __restrict__ k, const u16* __restrict__ projbf,
    float* __restrict__ kmax) {
  __shared__ __align__(16) u16 xt[64 * 72];
  __shared__ float wred[4];
  const int tid = threadIdx.x;
  const int bh = blockIdx.x >> 6, tb = blockIdx.x & 63;
  const int b = bh / Hn, h = bh % Hn;
  const int t0 = tb * 64;
  {
    const int t = tid >> 2, e0 = (tid & 3) * 16;
    const float* row = k + (((size_t)b * Tn + t0 + t) * Hn + h) * 64 + e0;
#pragma unroll
    for (int q4 = 0; q4 < 4; ++q4) {
      float4 vv = *reinterpret_cast<const float4*>(row + q4 * 4);
      ushort4 uu = make_ushort4(f2bf(vv.x * DATA_NORM), f2bf(vv.y * DATA_NORM),
                                f2bf(vv.z * DATA_NORM), f2bf(vv.w * DATA_NORM));
      *reinterpret_cast<ushort4*>(&xt[t * 72 + e0 + q4 * 4]) = uu;
    }
  }
  __syncthreads();
  const int lane = tid & 63, wv = tid >> 6;
  const int lj = lane & 15, lg = lane >> 4;
  bf16x8 a0 = ldb(&xt[(wv * 16 + lj) * 72 + lg * 8]);
  bf16x8 a1 = ldb(&xt[(wv * 16 + lj) * 72 + 32 + lg * 8]);
  float mx = -3e38f;
#pragma unroll
  for (int mt = 0; mt < 17; ++mt) {
    const u16* br = &projbf[(mt * 16 + lj) * 64 + lg * 8];
    f32x4 z = {0.f, 0.f, 0.f, 0.f};
    z = mfma16(a0, ldb(br), z);
    z = mfma16(a1, ldb(br + 32), z);
    int m = mt * 16 + lj;
    if (m < Mn)
      mx = fmaxf(mx, fmaxf(fmaxf(z[0], z[1]), fmaxf(z[2], z[3])));
  }
  mx = fmaxf(mx, __shfl_xor(mx, 1));
  mx = fmaxf(mx, __shfl_xor(mx, 2));
  mx = fmaxf(mx, __shfl_xor(mx, 4));
  mx = fmaxf(mx, __shfl_xor(mx, 8));
  mx = fmaxf(mx, __shfl_xor(mx, 16));
  mx = fmaxf(mx, __shfl_xor(mx, 32));
  if (lane == 0) wred[wv] = mx;
  __syncthreads();
  if (tid == 0)
    atomicMaxF(&kmax[bh], fmaxf(fmaxf(wred[0], wred[1]), fmaxf(wred[2], wred[3])));
}

// ---------------- stage_a: KV^T partial = V^T @ phi_k per chunk + z partial ----------------
// R6: stages raw f32 k inline (kn/diagk buffers removed).
__global__ __launch_bounds__(512) void stage_a(
    const float* __restrict__ v, const float* __restrict__ kk,
    const u16* __restrict__ projbf, const float* __restrict__ kmax,
    u16* __restrict__ kvT, float* __restrict__ zp) {
  __shared__ __align__(16) u16 knl[128 * 72];     // 18,432
  __shared__ __align__(16) u16 Vt[64 * 136];      // 17,408  (V^T [d][t])
  __shared__ __align__(16) u16 strip[288 * 40];   // 23,040  (phi_k^T [m][t-strip 32])
  __shared__ float dkl[128];
  const int tid = threadIdx.x, lane = tid & 63, wv = tid >> 6;
  const int lj = lane & 15, lg = lane >> 4;
  const int c = blockIdx.x & 31, bh = blockIdx.x >> 5;
  const int b = bh / Hn, h = bh % Hn;
  const int t0 = c * CH;
  const float kmx = kmax[bh];

  // stage raw k -> knl bf16 [128][72]; dkl[t] = 0.5*|kn_t|^2
#pragma unroll
  for (int l = 0; l < 2; ++l) {
    int idx = tid + l * 512;
    int t = idx >> 3, e8 = (idx & 7) * 8;
    const float* kr = &kk[(((size_t)b * Tn + t0 + t) * Hn + h) * 64 + e8];
    float4 u0 = *reinterpret_cast<const float4*>(kr);
    float4 u1 = *reinterpret_cast<const float4*>(kr + 4);
    float x0 = u0.x * DATA_NORM, x1 = u0.y * DATA_NORM;
    float x2 = u0.z * DATA_NORM, x3 = u0.w * DATA_NORM;
    float x4 = u1.x * DATA_NORM, x5 = u1.y * DATA_NORM;
    float x6 = u1.z * DATA_NORM, x7 = u1.w * DATA_NORM;
    float ss = x0*x0 + x1*x1 + x2*x2 + x3*x3 + x4*x4 + x5*x5 + x6*x6 + x7*x7;
    *reinterpret_cast<ushort4*>(&knl[t * 72 + e8]) =
        make_ushort4(f2bf(x0), f2bf(x1), f2bf(x2), f2bf(x3));
    *reinterpret_cast<ushort4*>(&knl[t * 72 + e8 + 4]) =
        make_ushort4(f2bf(x4), f2bf(x5), f2bf(x6), f2bf(x7));
    ss += __shfl_xor(ss, 1);
    ss += __shfl_xor(ss, 2);
    ss += __shfl_xor(ss, 4);
    if ((tid & 7) == 0) dkl[t] = 0.5f * ss;
  }
#pragma unroll
  for (int l = 0; l < 4; ++l) {   // V -> V^T LDS bf16
    int idx = tid + l * 512;
    int t = idx >> 4, d4 = (idx & 15) * 4;
    float4 vv = *reinterpret_cast<const float4*>(
        &v[(((size_t)b * Tn + t0 + t) * Hn + h) * 64 + d4]);
    Vt[(d4 + 0) * 136 + t] = f2bf(vv.x);
    Vt[(d4 + 1) * 136 + t] = f2bf(vv.y);
    Vt[(d4 + 2) * 136 + t] = f2bf(vv.z);
    Vt[(d4 + 3) * 136 + t] = f2bf(vv.w);
  }

  float zacc = 0.f;
  f32x4 kvacc[9];
#pragma unroll
  for (int i = 0; i < 9; ++i) kvacc[i] = (f32x4){0.f, 0.f, 0.f, 0.f};
  const int dtile = wv & 3, mg = wv >> 2;
  __syncthreads();

  for (int s = 0; s < 4; ++s) {
    if (s) __syncthreads();
    // P1: dd^T tiles (row=m, col=t), exp -> strip
#pragma unroll
    for (int i = 0; i < 5; ++i) {
      int idx = wv + 8 * i;
      if (idx < 36) {
        int mt = idx % 18, th = idx / 18;
        const u16* ar = &projbf[(mt * 16 + lj) * 64 + lg * 8];
        int trow = s * 32 + th * 16 + lj;
        const u16* br = &knl[trow * 72 + lg * 8];
        f32x4 z = {0.f, 0.f, 0.f, 0.f};
        z = mfma16(ldb(ar), ldb(br), z);
        z = mfma16(ldb(ar + 32), ldb(br + 32), z);
        float dgk = dkl[trow];
#pragma unroll
        for (int r = 0; r < 4; ++r) {
          int m = mt * 16 + lg * 4 + r;
          float val = (m < Mn) ? RATIO * (__expf(z[r] - dgk - kmx) + SM_EPS) : 0.f;
          strip[m * 40 + th * 16 + lj] = f2bf(val);
        }
      }
    }
    __syncthreads();
    // z partial (column sums over t of phi_k = row sums of strip)
    if (tid < MP) {
      const u16* srow = &strip[tid * 40];
#pragma unroll
      for (int o = 0; o < 32; o += 8) {
        bf16x8 vv = ldb(srow + o);
#pragma unroll
        for (int e = 0; e < 8; ++e) zacc += bf2f((u16)vv[e]);
      }
    }
    // KV^T mfma: A = V^T (row d, k=t), B = strip (col m, k=t)
    {
      bf16x8 av = ldb(&Vt[(dtile * 16 + lj) * 136 + s * 32 + lg * 8]);
#pragma unroll
      for (int i = 0; i < 9; ++i) {
        int mt = mg * 9 + i;
        kvacc[i] = mfma16(av, ldb(&strip[(mt * 16 + lj) * 40 + lg * 8]), kvacc[i]);
      }
    }
  }
  // write KV^T partial (row=d, col=m)
  size_t base = ((size_t)(bh * NC + c) * 64) * MP;
#pragma unroll
  for (int i = 0; i < 9; ++i) {
    int mt = mg * 9 + i;
#pragma unroll
    for (int r = 0; r < 4; ++r) {
      int d = dtile * 16 + lg * 4 + r;
      int m = mt * 16 + lj;
      kvT[base + (size_t)d * MP + m] = f2bf(kvacc[i][r]);
    }
  }
  if (tid < MP) zp[((size_t)bh * NC + c) * MP + tid] = zacc;
}

// ---------------- exclusive prefix scans over chunks ----------------
__global__ void scan_kv(u16* __restrict__ kvT) {
  int idx = blockIdx.x * 256 + threadIdx.x;          // 48*64*288
  if (idx >= BH * 64 * MP) return;
  int m = idx % MP;
  int r = idx / MP;
  int d = r % 64, bh = r / 64;
  u16* p = kvT + ((size_t)(bh * NC) * 64 + d) * MP + m;
  const size_t cs = (size_t)64 * MP;
  float acc = 0.f;
  for (int c = 0; c < NC; ++c) {
    float x = bf2f(p[c * cs]);
    p[c * cs] = f2bf(acc);
    acc += x;
  }
}

__global__ void scan_z(float* __restrict__ zp) {
  int idx = blockIdx.x * 256 + threadIdx.x;          // 48*288
  if (idx >= BH * MP) return;
  int m = idx % MP, bh = idx / MP;
  float* p = zp + (size_t)bh * NC * MP + m;
  float acc = 0.f;
  for (int c = 0; c < NC; ++c) {
    float x = p[(size_t)c * MP];
    p[(size_t)c * MP] = acc;
    acc += x;
  }
}

// ---------------- phik_fill: phi_k[t][m] for a bh-slice, direct global writes ----------------
__global__ __launch_bounds__(512) void phik_fill(
    const float* __restrict__ kk, const u16* __restrict__ projbf,
    const float* __restrict__ kmax, u16* __restrict__ phik, int bh0) {
  __shared__ __align__(16) u16 knl[128 * 72];
  __shared__ float dkl[128];
  const int tid = threadIdx.x, lane = tid & 63, wv = tid >> 6;
  const int lj = lane & 15, lg = lane >> 4;
  const int c = blockIdx.x & 31, bhl = blockIdx.x >> 5;
  const int bh = bh0 + bhl;
  const int b = bh / Hn, h = bh % Hn;
  const int t0 = c * CH;
  const float kmx = kmax[bh];

#pragma unroll
  for (int l = 0; l < 2; ++l) {
    int idx = tid + l * 512;
    int t = idx >> 3, e8 = (idx & 7) * 8;
    const float* kr = &kk[(((size_t)b * Tn + t0 + t) * Hn + h) * 64 + e8];
    float4 u0 = *reinterpret_cast<const float4*>(kr);
    float4 u1 = *reinterpret_cast<const float4*>(kr + 4);
    float x0 = u0.x * DATA_NORM, x1 = u0.y * DATA_NORM;
    float x2 = u0.z * DATA_NORM, x3 = u0.w * DATA_NORM;
    float x4 = u1.x * DATA_NORM, x5 = u1.y * DATA_NORM;
    float x6 = u1.z * DATA_NORM, x7 = u1.w * DATA_NORM;
    float ss = x0*x0 + x1*x1 + x2*x2 + x3*x3 + x4*x4 + x5*x5 + x6*x6 + x7*x7;
    *reinterpret_cast<ushort4*>(&knl[t * 72 + e8]) =
        make_ushort4(f2bf(x0), f2bf(x1), f2bf(x2), f2bf(x3));
    *reinterpret_cast<ushort4*>(&knl[t * 72 + e8 + 4]) =
        make_ushort4(f2bf(x4), f2bf(x5), f2bf(x6), f2bf(x7));
    ss += __shfl_xor(ss, 1);
    ss += __shfl_xor(ss, 2);
    ss += __shfl_xor(ss, 4);
    if ((tid & 7) == 0) dkl[t] = 0.5f * ss;
  }
  __syncthreads();

  u16* pout = phik + ((size_t)bhl * Tn + t0) * MP;
#pragma unroll 2
  for (int i = 0; i < 18; ++i) {      // 144 units: 18 m-tiles x 8 t-tiles
    int u = wv + 8 * i;
    int mt = u % 18, t8 = u / 18;
    const u16* ar = &projbf[(mt * 16 + lj) * 64 + lg * 8];
    const u16* br = &knl[(t8 * 16 + lj) * 72 + lg * 8];
    f32x4 z = {0.f, 0.f, 0.f, 0.f};
    z = mfma16(ldb(ar), ldb(br), z);
    z = mfma16(ldb(ar + 32), ldb(br + 32), z);
    int t = t8 * 16 + lj;             // D col = lj <-> kn row (t)
    float dgk = dkl[t];
    int mb = mt * 16 + lg * 4;        // D row = lg*4+r <-> proj row (m)
    float vals[4];
#pragma unroll
    for (int r = 0; r < 4; ++r) {
      int m = mb + r;
      vals[r] = (m < Mn) ? RATIO * (__expf(z[r] - dgk - kmx) + SM_EPS) : 0.f;
    }
    *reinterpret_cast<ushort4*>(&pout[(size_t)t * MP + mb]) =
        make_ushort4(f2bf(vals[0]), f2bf(vals[1]), f2bf(vals[2]), f2bf(vals[3]));
  }
}

// ---------------- stage_c4: global-fed MFMA stream, 4 barriers, bh-sliced ----------------
__global__ __launch_bounds__(512, 4) void stage_c4(
    const float* __restrict__ v, const u16* __restrict__ phiq,
    const u16* __restrict__ phik, const u16* __restrict__ kvT,
    const float* __restrict__ zp, float* __restrict__ out, int bh0) {
  __shared__ __align__(16) u16 Albuf[128 * 136];   // 34,816
  __shared__ __align__(16) u16 Vt[64 * 136];       // 17,408
  __shared__ float zl[MP];
  __shared__ float rs2[128 * 8];
  __shared__ float qzb[128];
  __shared__ float den[128];

  const int tid = threadIdx.x, lane = tid & 63, wv = tid >> 6;
  const int lj = lane & 15, lg = lane >> 4;
  const int c = blockIdx.x & 31, bhl = blockIdx.x >> 5;
  const int bh = bh0 + bhl;
  const int b = bh / Hn, h = bh % Hn;
  const int t0 = c * CH;
  const size_t qbase = ((size_t)bh * Tn + t0) * MP;
  const size_t pkbase = ((size_t)bhl * Tn + t0) * MP;   // slice-local phik

  if (tid < MP) zl[tid] = zp[((size_t)bh * NC + c) * MP + tid];
#pragma unroll
  for (int l = 0; l < 5; ++l) {   // zero Albuf (2176 uint4)
    int idx = tid + l * 512;
    if (idx < 2176)
      *reinterpret_cast<uint4*>(&Albuf[idx * 8]) = make_uint4(0, 0, 0, 0);
  }
  for (int idx = tid; idx < 128 * 8; idx += 512) rs2[idx] = 0.f;
#pragma unroll
  for (int l = 0; l < 4; ++l) {   // stage V^T
    int idx = tid + l * 512;
    int t = idx >> 4, d4 = (idx & 15) * 4;
    float4 vv = *reinterpret_cast<const float4*>(
        &v[(((size_t)b * Tn + t0 + t) * Hn + h) * 64 + d4]);
    Vt[(d4 + 0) * 136 + t] = f2bf(vv.x);
    Vt[(d4 + 1) * 136 + t] = f2bf(vv.y);
    Vt[(d4 + 2) * 136 + t] = f2bf(vv.z);
    Vt[(d4 + 3) * 136 + t] = f2bf(vv.w);
  }
  __syncthreads();   // B1

  // P2: causal QK^T tiles, A/B straight from global, no inter-tile barriers
  for (int kk = 0; kk < 5; ++kk) {
    int idx = wv + 8 * kk;
    if (idx >= 36) break;
    const int tt = cTT[idx], tp = cTP[idx];
    bf16x8 Af[9], Bf[9];
#pragma unroll
    for (int ks = 0; ks < 9; ++ks) {
      Af[ks] = ldb(&phiq[qbase + (size_t)(tt * 16 + lj) * MP + ks * 32 + lg * 8]);
      Bf[ks] = ldb(&phik[pkbase + (size_t)(tp * 16 + lj) * MP + ks * 32 + lg * 8]);
    }
    f32x4 a = {0.f, 0.f, 0.f, 0.f};
#pragma unroll
    for (int ks = 0; ks < 9; ++ks) a = mfma16(Af[ks], Bf[ks], a);
    if (tt == tp) {
#pragma unroll
      for (int r = 0; r < 4; ++r)
        if (lj > lg * 4 + r) a[r] = 0.f;
    }
    f32x4 s = a;
#pragma unroll
    for (int r = 0; r < 4; ++r) {
      s[r] += __shfl_xor(s[r], 1);
      s[r] += __shfl_xor(s[r], 2);
      s[r] += __shfl_xor(s[r], 4);
      s[r] += __shfl_xor(s[r], 8);
    }
    if (lj == 0) {
#pragma unroll
      for (int r = 0; r < 4; ++r) rs2[(tt * 16 + lg * 4 + r) * 8 + tp] = s[r];
    }
#pragma unroll
    for (int r = 0; r < 4; ++r)
      Albuf[(tt * 16 + lg * 4 + r) * 136 + tp * 16 + lj] = f2bf(a[r]);
  }

  // prefetch P3/P4 operands (lands while other waves finish P2)
  const size_t kvbase = ((size_t)(bh * NC + c) * 64) * MP;
  bf16x8 qa[9];
#pragma unroll
  for (int ks = 0; ks < 9; ++ks)
    qa[ks] = ldb(&phiq[qbase + (size_t)(wv * 16 + lj) * MP + ks * 32 + lg * 8]);
  bf16x8 kbA[4], kbB[4];
#pragma unroll
  for (int dt = 0; dt < 4; ++dt)
    kbA[dt] = ldb(&kvT[kvbase + (size_t)(dt * 16 + lj) * MP + lg * 8]);
  __syncthreads();   // B2

  // P3: O += A @ V (triangular k-step skip)
  f32x4 oacc[4];
#pragma unroll
  for (int dt = 0; dt < 4; ++dt) oacc[dt] = (f32x4){0.f, 0.f, 0.f, 0.f};
  const int ksteps = (wv >> 1) + 1;
  for (int ks = 0; ks < ksteps; ++ks) {
    bf16x8 af = ldb(&Albuf[(wv * 16 + lj) * 136 + ks * 32 + lg * 8]);
#pragma unroll
    for (int dt = 0; dt < 4; ++dt) {
      bf16x8 bf = ldb(&Vt[(dt * 16 + lj) * 136 + ks * 32 + lg * 8]);
      oacc[dt] = mfma16(af, bf, oacc[dt]);
    }
  }

  // P4: O += phi_q @ S_prev; B double-buffered in regs; fused qz
  float qz = 0.f;
#pragma unroll
  for (int ks = 0; ks < 9; ++ks) {
    const bf16x8* cur = (ks & 1) ? kbB : kbA;
    bf16x8* nxt = (ks & 1) ? kbA : kbB;
    if (ks < 8) {
      int m1 = (ks + 1) * 32;
#pragma unroll
      for (int dt = 0; dt < 4; ++dt)
        nxt[dt] = ldb(&kvT[kvbase + (size_t)(dt * 16 + lj) * MP + m1 + lg * 8]);
    }
#pragma unroll
    for (int e = 0; e < 8; ++e)
      qz += bf2f((u16)qa[ks][e]) * zl[ks * 32 + lg * 8 + e];
#pragma unroll
    for (int dt = 0; dt < 4; ++dt)
      oacc[dt] = mfma16(qa[ks], cur[dt], oacc[dt]);
  }
  qz += __shfl_xor(qz, 16);
  qz += __shfl_xor(qz, 32);
  if (lane < 16) qzb[wv * 16 + lane] = qz;
  __syncthreads();   // B3

  if (tid < 128) {
    float s = qzb[tid] + N_EPS;
#pragma unroll
    for (int t2 = 0; t2 < 8; ++t2) s += rs2[tid * 8 + t2];
    den[tid] = s;
  }
  __syncthreads();   // B4

#pragma unroll
  for (int dt = 0; dt < 4; ++dt) {
#pragma unroll
    for (int r = 0; r < 4; ++r) {
      int tl = wv * 16 + lg * 4 + r;
      float o = oacc[dt][r] / den[tl];
      out[(((size_t)b * Tn + t0 + tl) * Hn + h) * 64 + dt * 16 + lj] = o;
    }
  }
}

extern "C" void kernel_launch(void* const* d_in, const int* in_sizes, int n_in,
                              void* d_out, int out_size, void* d_ws, size_t ws_size,
                              hipStream_t stream) {
  const float* q = (const float*)d_in[0];
  const float* k = (const float*)d_in[1];
  const float* v = (const float*)d_in[2];
  const float* proj = (const float*)d_in[3];
  float* out = (float*)d_out;

  char* ws = (char*)d_ws;
  const size_t phiq_b = (size_t)BH * Tn * MP * 2;        // 113,246,208
  const size_t kvT_b  = (size_t)BH * NC * 64 * MP * 2;   //  56,623,104
  const size_t zp_b   = (size_t)BH * NC * MP * 4;        //   1,769,472
  const size_t pj_b   = (size_t)MP * 64 * 2;             //      36,864
  const size_t km_b   = 256;

  size_t off = 0;
  u16*   phiq  = (u16*)(ws + off);  off += phiq_b;
  u16*   kvT   = (u16*)(ws + off);  off += kvT_b;
  float* zp    = (float*)(ws + off); off += zp_b;
  u16*   projbf= (u16*)(ws + off);  off += pj_b;
  float* kmax  = (float*)(ws + off); off += km_b;
  u16*   phik  = (u16*)(ws + off);
  // pick largest bh-slice whose phik fits: off = 171.7MB; eighth tier (6 bh,
  // 14.2MB) totals 185.8MB < 197.6MB proven-working -> guaranteed fit.
  const size_t per_bh = (size_t)Tn * MP * 2;
  size_t avail = (ws_size > off) ? (ws_size - off) : 0;
  int nbh = 6;
  if (avail >= 48 * per_bh)      nbh = 48;
  else if (avail >= 24 * per_bh) nbh = 24;
  else if (avail >= 12 * per_bh) nbh = 12;

  prep<<<72, 256, 0, stream>>>(proj, projbf, kmax);
  feat_k<<<BH * 64, 256, 0, stream>>>(k, projbf, kmax);
  feat_q<<<BH * 64, 256, 0, stream>>>(q, projbf, phiq);
  stage_a<<<BH * NC, 512, 0, stream>>>(v, k, projbf, kmax, kvT, zp);
  scan_kv<<<(BH * 64 * MP) / 256, 256, 0, stream>>>(kvT);
  scan_z<<<(BH * MP + 255) / 256, 256, 0, stream>>>(zp);
  for (int bh0 = 0; bh0 < BH; bh0 += nbh) {
    phik_fill<<<nbh * NC, 512, 0, stream>>>(k, projbf, kmax, phik, bh0);
    stage_c4<<<nbh * NC, 512, 0, stream>>>(v, phiq, phik, kvT, zp, out, bh0);
  }
}